// Round 1
// baseline (1442.068 us; speedup 1.0000x reference)
//
#include <hip/hip_runtime.h>

#define TOKENS 8192
#define IN_F   4096
#define OUT_F  11008

#define BM 256
#define BN 256
#define BK 64
#define NT (IN_F / BK)      // 64 K-tiles
#define TM (TOKENS / BM)    // 32
#define TN (OUT_F / BN)     // 43
#define NWG (TM * TN)       // 1376, divisible by 8 -> simple XCD swizzle bijective

#define LDS_TILE 32768      // 256 rows * 128 B
#define ROWB 128            // LDS row bytes (64 bf16)
#define GROWB (IN_F * 2)    // global row bytes = 8192

typedef __attribute__((ext_vector_type(8))) short bf16x8;
typedef __attribute__((ext_vector_type(4))) float floatx4;

__device__ __forceinline__ unsigned short f32_to_bf16(float f) {
  union { float f; unsigned int u; } v; v.f = f;
  unsigned int r = v.u + 0x7FFFu + ((v.u >> 16) & 1u);   // round-to-nearest-even
  return (unsigned short)(r >> 16);
}

__device__ __forceinline__ void gload_lds16(const void* g, void* l) {
  __builtin_amdgcn_global_load_lds(
      (const __attribute__((address_space(1))) void*)g,
      (__attribute__((address_space(3))) void*)l,
      16, 0, 0);
}

__device__ __forceinline__ void phase_split() {
  __builtin_amdgcn_sched_barrier(0);
  __builtin_amdgcn_s_barrier();
  __builtin_amdgcn_sched_barrier(0);
}

// ---- x: fp32 -> bf16 (8 elems/thread, 16B stores) ----
__global__ __launch_bounds__(256) void convert_x_kernel(
    const float* __restrict__ x, unsigned short* __restrict__ xb) {
  int idx = (blockIdx.x * 256 + threadIdx.x) * 8;
  const float4* p = (const float4*)(x + idx);
  float4 f0 = p[0], f1 = p[1];
  bf16x8 o;
  o[0] = (short)f32_to_bf16(f0.x); o[1] = (short)f32_to_bf16(f0.y);
  o[2] = (short)f32_to_bf16(f0.z); o[3] = (short)f32_to_bf16(f0.w);
  o[4] = (short)f32_to_bf16(f1.x); o[5] = (short)f32_to_bf16(f1.y);
  o[6] = (short)f32_to_bf16(f1.z); o[7] = (short)f32_to_bf16(f1.w);
  *(bf16x8*)(xb + idx) = o;
}

// ---- W: int32 (values in [-128,127]) -> bf16, exact ----
__global__ __launch_bounds__(256) void convert_w_kernel(
    const int* __restrict__ w, unsigned short* __restrict__ wb) {
  int idx = (blockIdx.x * 256 + threadIdx.x) * 8;
  const int4* p = (const int4*)(w + idx);
  int4 a = p[0], b = p[1];
  bf16x8 o;
  o[0] = (short)f32_to_bf16((float)a.x); o[1] = (short)f32_to_bf16((float)a.y);
  o[2] = (short)f32_to_bf16((float)a.z); o[3] = (short)f32_to_bf16((float)a.w);
  o[4] = (short)f32_to_bf16((float)b.x); o[5] = (short)f32_to_bf16((float)b.y);
  o[6] = (short)f32_to_bf16((float)b.z); o[7] = (short)f32_to_bf16((float)b.w);
  *(bf16x8*)(wb + idx) = o;
}

// ---- 256x256 8-phase bf16 GEMM (m201 template): C = A * B^T, fused scale+bias
// 512 threads = 8 waves (2M x 4N). BK=64, double-buffered 128 KiB LDS.
// Per K-tile: 4 phases, quadrants (mh0,nh0)(mh0,nh1)(mh1,nh1)(mh1,nh0),
// one half-tile staged per phase, counted vmcnt(4) once per K-tile.
// LDS 16B-granule XOR swizzle (g ^= row&7): linear gload_lds dest,
// inverse-swizzled GLOBAL source, swizzled ds_read (rule #21).
__global__ __launch_bounds__(512, 2) void qlinear_gemm(
    const unsigned short* __restrict__ A,
    const unsigned short* __restrict__ B,
    const float* __restrict__ scales,
    const float* __restrict__ bias,
    float* __restrict__ out) {
  __shared__ __align__(16) char As[2 * LDS_TILE];
  __shared__ __align__(16) char Bs[2 * LDS_TILE];

  // XCD-aware bijective swizzle (NWG % 8 == 0)
  const int wg   = blockIdx.x;
  const int wgid = (wg & 7) * (NWG / 8) + (wg >> 3);
  const int tm   = wgid / TN;
  const int tn   = wgid - tm * TN;
  const int m0   = tm * BM;
  const int n0   = tn * BN;

  const int t    = threadIdx.x;
  const int lane = t & 63;
  const int w    = t >> 6;   // 0..7
  const int wr   = w >> 2;   // 0..1 (M)
  const int wc   = w & 3;    // 0..3 (N)

  // ---- staging geometry ----
  // One gload instr: 512 thr x 16B = 8 KiB = 64 rows. Wave w covers rows
  // w*8..w*8+7; lane l -> row w*8+(l>>3), LDS granule l&7. Source granule
  // pre-swizzled: (l&7) ^ (l>>3)  (row&7 == l>>3 by construction).
  const int srow = (w << 3) + (lane >> 3);
  const int sgx  = ((lane & 7) ^ (lane >> 3)) << 4;
  const char* gA = (const char*)A + (size_t)(m0 + srow) * GROWB + sgx;
  const char* gB = (const char*)B + (size_t)(n0 + srow) * GROWB + sgx;
  char* lA = As + (w << 3) * ROWB;   // wave-uniform base; HW adds lane*16
  char* lB = Bs + (w << 3) * ROWB;

#define STAGE_A(tt, h) do {                                                  \
    const char* g_ = gA + (size_t)(tt) * (BK * 2) + (size_t)((h)*128) * GROWB; \
    char* l_ = lA + ((tt) & 1) * LDS_TILE + ((h) * 128) * ROWB;              \
    gload_lds16(g_, l_);                                                     \
    gload_lds16(g_ + (size_t)64 * GROWB, l_ + 64 * ROWB);                    \
  } while (0)

#define STAGE_B(tt, h) do {                                                  \
    const char* g_ = gB + (size_t)(tt) * (BK * 2) + (size_t)((h)*128) * GROWB; \
    char* l_ = lB + ((tt) & 1) * LDS_TILE + ((h) * 128) * ROWB;              \
    gload_lds16(g_, l_);                                                     \
    gload_lds16(g_ + (size_t)64 * GROWB, l_ + 64 * ROWB);                    \
  } while (0)

  // ---- read geometry: frag row = base + (lane&15); row&7 == lane&7 ----
  const int c0 = (((lane >> 4) ^ (lane & 7)) << 4);        // kk=0 granule byte
  const int c1 = ((((lane >> 4) | 4) ^ (lane & 7)) << 4);  // kk=1 granule byte
  const char* rA = As + (wr * 128 + (lane & 15)) * ROWB;
  const char* rB = Bs + (wc * 64 + (lane & 15)) * ROWB;

#define LDA(dst, mh, m, off, ck) \
  dst = *(const bf16x8*)(rA + (off) + ((mh) * 64 + (m) * 16) * ROWB + (ck))
#define LDB(dst, ni, off, ck) \
  dst = *(const bf16x8*)(rB + (off) + (ni) * 16 * ROWB + (ck))

  floatx4 acc[8][4];
#pragma unroll
  for (int i = 0; i < 8; ++i)
#pragma unroll
    for (int j = 0; j < 4; ++j) acc[i][j] = (floatx4){0.f, 0.f, 0.f, 0.f};

  // ---- prologue: tile0 {A0,A1,B0,B1} then tile1 {B0,A0}; wait tile0 (4 left)
  STAGE_A(0, 0); STAGE_A(0, 1); STAGE_B(0, 0); STAGE_B(0, 1);
  STAGE_B(1, 0); STAGE_A(1, 0);
  asm volatile("s_waitcnt vmcnt(4)" ::: "memory");
  phase_split();

  bf16x8 a[4][2];   // current A mh-half (reused mh0 -> mh1)
  bf16x8 bq[4][2];  // all 4 B n-frags, live across the 4 phases

  for (int kt = 0; kt < NT; ++kt) {
    const int off = (kt & 1) * LDS_TILE;

    // ============ phase 0: reads A[mh0](8) + B[nh0](4); stage B1(kt+1) ======
#pragma unroll
    for (int m = 0; m < 4; ++m) { LDA(a[m][0], 0, m, off, c0); LDA(a[m][1], 0, m, off, c1); }
#pragma unroll
    for (int n = 0; n < 2; ++n) { LDB(bq[n][0], n, off, c0); LDB(bq[n][1], n, off, c1); }
    if (kt + 1 < NT) STAGE_B(kt + 1, 1);
    phase_split();
    asm volatile("s_waitcnt lgkmcnt(0)" ::: "memory");
    __builtin_amdgcn_sched_barrier(0);
    __builtin_amdgcn_s_setprio(1);
#pragma unroll
    for (int m = 0; m < 4; ++m)
#pragma unroll
      for (int n = 0; n < 2; ++n) {
        acc[m][n] = __builtin_amdgcn_mfma_f32_16x16x32_bf16(a[m][0], bq[n][0], acc[m][n], 0, 0, 0);
        acc[m][n] = __builtin_amdgcn_mfma_f32_16x16x32_bf16(a[m][1], bq[n][1], acc[m][n], 0, 0, 0);
      }
    __builtin_amdgcn_s_setprio(0);
    phase_split();

    // ============ phase 1: reads B[nh1](4); stage A1(kt+1) ==================
#pragma unroll
    for (int n = 2; n < 4; ++n) { LDB(bq[n][0], n, off, c0); LDB(bq[n][1], n, off, c1); }
    if (kt + 1 < NT) STAGE_A(kt + 1, 1);
    phase_split();
    asm volatile("s_waitcnt lgkmcnt(0)" ::: "memory");
    __builtin_amdgcn_sched_barrier(0);
    __builtin_amdgcn_s_setprio(1);
#pragma unroll
    for (int m = 0; m < 4; ++m)
#pragma unroll
      for (int n = 2; n < 4; ++n) {
        acc[m][n] = __builtin_amdgcn_mfma_f32_16x16x32_bf16(a[m][0], bq[n][0], acc[m][n], 0, 0, 0);
        acc[m][n] = __builtin_amdgcn_mfma_f32_16x16x32_bf16(a[m][1], bq[n][1], acc[m][n], 0, 0, 0);
      }
    __builtin_amdgcn_s_setprio(0);
    phase_split();

    // ============ phase 2: reads A[mh1](8); stage B0(kt+2) into cur buf =====
    // (B-half0 of cur is dead: all its reads completed by end of phase 1)
#pragma unroll
    for (int m = 0; m < 4; ++m) { LDA(a[m][0], 1, m, off, c0); LDA(a[m][1], 1, m, off, c1); }
    if (kt + 2 < NT) STAGE_B(kt + 2, 0);
    phase_split();
    asm volatile("s_waitcnt lgkmcnt(0)" ::: "memory");
    __builtin_amdgcn_sched_barrier(0);
    __builtin_amdgcn_s_setprio(1);
#pragma unroll
    for (int m = 0; m < 4; ++m)
#pragma unroll
      for (int n = 2; n < 4; ++n) {
        acc[4 + m][n] = __builtin_amdgcn_mfma_f32_16x16x32_bf16(a[m][0], bq[n][0], acc[4 + m][n], 0, 0, 0);
        acc[4 + m][n] = __builtin_amdgcn_mfma_f32_16x16x32_bf16(a[m][1], bq[n][1], acc[4 + m][n], 0, 0, 0);
      }
    __builtin_amdgcn_s_setprio(0);
    phase_split();

    // ============ phase 3: no reads; stage A0(kt+2); counted vmcnt ==========
    // (A-half0 of cur is dead: mh0 read at p0, mh1 at p2)
    if (kt + 2 < NT) STAGE_A(kt + 2, 0);
    phase_split();
    __builtin_amdgcn_s_setprio(1);
#pragma unroll
    for (int m = 0; m < 4; ++m)
#pragma unroll
      for (int n = 0; n < 2; ++n) {
        acc[4 + m][n] = __builtin_amdgcn_mfma_f32_16x16x32_bf16(a[m][0], bq[n][0], acc[4 + m][n], 0, 0, 0);
        acc[4 + m][n] = __builtin_amdgcn_mfma_f32_16x16x32_bf16(a[m][1], bq[n][1], acc[4 + m][n], 0, 0, 0);
      }
    __builtin_amdgcn_s_setprio(0);
    // wait for tile kt+1's 4 half-tiles; 4 loads (B0,A0 of kt+2) stay in flight
    if (kt + 2 < NT) {
      asm volatile("s_waitcnt vmcnt(4)" ::: "memory");
    } else if (kt + 1 < NT) {
      asm volatile("s_waitcnt vmcnt(0)" ::: "memory");
    }
    phase_split();
  }

#undef STAGE_A
#undef STAGE_B
#undef LDA
#undef LDB

  // ---- epilogue: D row=(lane>>4)*4+r (M), col=lane&15 (N); fused scale+bias
  const int rq   = (lane >> 4) << 2;
  const int colb = n0 + wc * 64 + (lane & 15);
#pragma unroll
  for (int ni = 0; ni < 4; ++ni) {
    const int col = colb + ni * 16;
    const float s  = scales[col];
    const float bb = bias[col];
#pragma unroll
    for (int mi = 0; mi < 8; ++mi) {
      const int rowb = m0 + wr * 128 + mi * 16 + rq;
#pragma unroll
      for (int r = 0; r < 4; ++r)
        out[(size_t)(rowb + r) * OUT_F + col] = acc[mi][ni][r] * s + bb;
    }
  }
}

extern "C" void kernel_launch(void* const* d_in, const int* in_sizes, int n_in,
                              void* d_out, int out_size, void* d_ws, size_t ws_size,
                              hipStream_t stream) {
  const float* x      = (const float*)d_in[0];
  const int*   wq     = (const int*)d_in[1];    // int8 values stored as int32 per harness contract
  const float* scales = (const float*)d_in[2];
  const float* bias   = (const float*)d_in[3];
  float* out = (float*)d_out;

  unsigned short* Xb = (unsigned short*)d_ws;                                      // 67 MB
  unsigned short* Wb = (unsigned short*)((char*)d_ws + (size_t)TOKENS * IN_F * 2); // +90 MB

  convert_x_kernel<<<TOKENS * IN_F / (256 * 8), 256, 0, stream>>>(x, Xb);
  convert_w_kernel<<<OUT_F * IN_F / (256 * 8), 256, 0, stream>>>(wq, Wb);
  qlinear_gemm<<<NWG, 512, 0, stream>>>(Xb, Wb, scales, bias, out);
}

// Round 2
// 1376.606 us; speedup vs baseline: 1.0476x; 1.0476x over previous
//
#include <hip/hip_runtime.h>

#define TOKENS 8192
#define IN_F   4096
#define OUT_F  11008

#define BM 256
#define BN 256
#define BK 64
#define NT (IN_F / BK)      // 64 K-tiles
#define TM (TOKENS / BM)    // 32
#define TN (OUT_F / BN)     // 43
#define NWG (TM * TN)       // 1376 = 8 XCDs * 172

#define LDS_TILE 32768      // 256 rows * 128 B
#define ROWB 128            // LDS row bytes (64 bf16)
#define GROWB (IN_F * 2)    // global row bytes = 8192

typedef __attribute__((ext_vector_type(8))) short bf16x8;
typedef __attribute__((ext_vector_type(4))) float floatx4;

__device__ __forceinline__ unsigned short f32_to_bf16(float f) {
  union { float f; unsigned int u; } v; v.f = f;
  unsigned int r = v.u + 0x7FFFu + ((v.u >> 16) & 1u);   // round-to-nearest-even
  return (unsigned short)(r >> 16);
}

__device__ __forceinline__ void gload_lds16(const void* g, void* l) {
  __builtin_amdgcn_global_load_lds(
      (const __attribute__((address_space(1))) void*)g,
      (__attribute__((address_space(3))) void*)l,
      16, 0, 0);
}

__device__ __forceinline__ void phase_split() {
  __builtin_amdgcn_sched_barrier(0);
  __builtin_amdgcn_s_barrier();
  __builtin_amdgcn_sched_barrier(0);
}

// ---- x: fp32 -> bf16 (8 elems/thread, 16B stores) ----
__global__ __launch_bounds__(256) void convert_x_kernel(
    const float* __restrict__ x, unsigned short* __restrict__ xb) {
  int idx = (blockIdx.x * 256 + threadIdx.x) * 8;
  const float4* p = (const float4*)(x + idx);
  float4 f0 = p[0], f1 = p[1];
  bf16x8 o;
  o[0] = (short)f32_to_bf16(f0.x); o[1] = (short)f32_to_bf16(f0.y);
  o[2] = (short)f32_to_bf16(f0.z); o[3] = (short)f32_to_bf16(f0.w);
  o[4] = (short)f32_to_bf16(f1.x); o[5] = (short)f32_to_bf16(f1.y);
  o[6] = (short)f32_to_bf16(f1.z); o[7] = (short)f32_to_bf16(f1.w);
  *(bf16x8*)(xb + idx) = o;
}

// ---- W: int32 (values in [-128,127]) -> bf16, exact ----
__global__ __launch_bounds__(256) void convert_w_kernel(
    const int* __restrict__ w, unsigned short* __restrict__ wb) {
  int idx = (blockIdx.x * 256 + threadIdx.x) * 8;
  const int4* p = (const int4*)(w + idx);
  int4 a = p[0], b = p[1];
  bf16x8 o;
  o[0] = (short)f32_to_bf16((float)a.x); o[1] = (short)f32_to_bf16((float)a.y);
  o[2] = (short)f32_to_bf16((float)a.z); o[3] = (short)f32_to_bf16((float)a.w);
  o[4] = (short)f32_to_bf16((float)b.x); o[5] = (short)f32_to_bf16((float)b.y);
  o[6] = (short)f32_to_bf16((float)b.z); o[7] = (short)f32_to_bf16((float)b.w);
  *(bf16x8*)(wb + idx) = o;
}

// ---- 256x256 8-phase bf16 GEMM (m201 template): C = A * B^T, fused scale+bias
// 512 threads = 8 waves (2M x 4N). BK=64, double-buffered 128 KiB LDS.
// Per K-tile: 4 phases, quadrants (mh0,nh0)(mh0,nh1)(mh1,nh1)(mh1,nh0),
// one half-tile staged per phase, counted vmcnt(4) once per K-tile.
// LDS 16B-granule XOR swizzle (g ^= row&7): linear gload_lds dest,
// inverse-swizzled GLOBAL source, swizzled ds_read (rule #21).
//
// R1 change: 2-D L2-aware XCD mapping. Blocks dispatch round-robin over the
// 8 XCDs (xcd = blockIdx%8, slot s = blockIdx/8, 172 slots each). Each XCD
// owns a 4-row tm band (tm = xcd*4 + (s&3)) and walks tn column-major
// (tn = s>>2). The ~32 concurrent blocks per XCD then form a 4x8 (tm x tn)
// rectangle: A chunks shared 8-way, B chunks 4-way, hot set ~768 KB in the
// 4 MiB XCD L2 -> B no longer streams from L3/HBM (was 1.57 GB HBM fetch).
__global__ __launch_bounds__(512, 2) void qlinear_gemm(
    const unsigned short* __restrict__ A,
    const unsigned short* __restrict__ B,
    const float* __restrict__ scales,
    const float* __restrict__ bias,
    float* __restrict__ out) {
  __shared__ __align__(16) char As[2 * LDS_TILE];
  __shared__ __align__(16) char Bs[2 * LDS_TILE];

  const int wg  = blockIdx.x;
  const int xcd = wg & 7;
  const int s   = wg >> 3;          // 0..171
  const int tm  = xcd * 4 + (s & 3);
  const int tn  = s >> 2;
  const int m0  = tm * BM;
  const int n0  = tn * BN;

  const int t    = threadIdx.x;
  const int lane = t & 63;
  const int w    = t >> 6;   // 0..7
  const int wr   = w >> 2;   // 0..1 (M)
  const int wc   = w & 3;    // 0..3 (N)

  // ---- staging geometry ----
  // One gload instr: 512 thr x 16B = 8 KiB = 64 rows. Wave w covers rows
  // w*8..w*8+7; lane l -> row w*8+(l>>3), LDS granule l&7. Source granule
  // pre-swizzled: (l&7) ^ (l>>3)  (row&7 == l>>3 by construction).
  const int srow = (w << 3) + (lane >> 3);
  const int sgx  = ((lane & 7) ^ (lane >> 3)) << 4;
  const char* gA = (const char*)A + (size_t)(m0 + srow) * GROWB + sgx;
  const char* gB = (const char*)B + (size_t)(n0 + srow) * GROWB + sgx;
  char* lA = As + (w << 3) * ROWB;   // wave-uniform base; HW adds lane*16
  char* lB = Bs + (w << 3) * ROWB;

#define STAGE_A(tt, h) do {                                                  \
    const char* g_ = gA + (size_t)(tt) * (BK * 2) + (size_t)((h)*128) * GROWB; \
    char* l_ = lA + ((tt) & 1) * LDS_TILE + ((h) * 128) * ROWB;              \
    gload_lds16(g_, l_);                                                     \
    gload_lds16(g_ + (size_t)64 * GROWB, l_ + 64 * ROWB);                    \
  } while (0)

#define STAGE_B(tt, h) do {                                                  \
    const char* g_ = gB + (size_t)(tt) * (BK * 2) + (size_t)((h)*128) * GROWB; \
    char* l_ = lB + ((tt) & 1) * LDS_TILE + ((h) * 128) * ROWB;              \
    gload_lds16(g_, l_);                                                     \
    gload_lds16(g_ + (size_t)64 * GROWB, l_ + 64 * ROWB);                    \
  } while (0)

  // ---- read geometry: frag row = base + (lane&15); row&7 == lane&7 ----
  const int c0 = (((lane >> 4) ^ (lane & 7)) << 4);        // kk=0 granule byte
  const int c1 = ((((lane >> 4) | 4) ^ (lane & 7)) << 4);  // kk=1 granule byte
  const char* rA = As + (wr * 128 + (lane & 15)) * ROWB;
  const char* rB = Bs + (wc * 64 + (lane & 15)) * ROWB;

#define LDA(dst, mh, m, off, ck) \
  dst = *(const bf16x8*)(rA + (off) + ((mh) * 64 + (m) * 16) * ROWB + (ck))
#define LDB(dst, ni, off, ck) \
  dst = *(const bf16x8*)(rB + (off) + (ni) * 16 * ROWB + (ck))

  floatx4 acc[8][4];
#pragma unroll
  for (int i = 0; i < 8; ++i)
#pragma unroll
    for (int j = 0; j < 4; ++j) acc[i][j] = (floatx4){0.f, 0.f, 0.f, 0.f};

  // ---- prologue: tile0 {A0,A1,B0,B1} then tile1 {B0,A0}; wait tile0 (4 left)
  STAGE_A(0, 0); STAGE_A(0, 1); STAGE_B(0, 0); STAGE_B(0, 1);
  STAGE_B(1, 0); STAGE_A(1, 0);
  asm volatile("s_waitcnt vmcnt(4)" ::: "memory");
  phase_split();

  bf16x8 a[4][2];   // current A mh-half (reused mh0 -> mh1)
  bf16x8 bq[4][2];  // all 4 B n-frags, live across the 4 phases

  for (int kt = 0; kt < NT; ++kt) {
    const int off = (kt & 1) * LDS_TILE;

    // ============ phase 0: reads A[mh0](8) + B[nh0](4); stage B1(kt+1) ======
#pragma unroll
    for (int m = 0; m < 4; ++m) { LDA(a[m][0], 0, m, off, c0); LDA(a[m][1], 0, m, off, c1); }
#pragma unroll
    for (int n = 0; n < 2; ++n) { LDB(bq[n][0], n, off, c0); LDB(bq[n][1], n, off, c1); }
    if (kt + 1 < NT) STAGE_B(kt + 1, 1);
    phase_split();
    asm volatile("s_waitcnt lgkmcnt(0)" ::: "memory");
    __builtin_amdgcn_sched_barrier(0);
    __builtin_amdgcn_s_setprio(1);
#pragma unroll
    for (int m = 0; m < 4; ++m)
#pragma unroll
      for (int n = 0; n < 2; ++n) {
        acc[m][n] = __builtin_amdgcn_mfma_f32_16x16x32_bf16(a[m][0], bq[n][0], acc[m][n], 0, 0, 0);
        acc[m][n] = __builtin_amdgcn_mfma_f32_16x16x32_bf16(a[m][1], bq[n][1], acc[m][n], 0, 0, 0);
      }
    __builtin_amdgcn_s_setprio(0);
    phase_split();

    // ============ phase 1: reads B[nh1](4); stage A1(kt+1) ==================
#pragma unroll
    for (int n = 2; n < 4; ++n) { LDB(bq[n][0], n, off, c0); LDB(bq[n][1], n, off, c1); }
    if (kt + 1 < NT) STAGE_A(kt + 1, 1);
    phase_split();
    asm volatile("s_waitcnt lgkmcnt(0)" ::: "memory");
    __builtin_amdgcn_sched_barrier(0);
    __builtin_amdgcn_s_setprio(1);
#pragma unroll
    for (int m = 0; m < 4; ++m)
#pragma unroll
      for (int n = 2; n < 4; ++n) {
        acc[m][n] = __builtin_amdgcn_mfma_f32_16x16x32_bf16(a[m][0], bq[n][0], acc[m][n], 0, 0, 0);
        acc[m][n] = __builtin_amdgcn_mfma_f32_16x16x32_bf16(a[m][1], bq[n][1], acc[m][n], 0, 0, 0);
      }
    __builtin_amdgcn_s_setprio(0);
    phase_split();

    // ============ phase 2: reads A[mh1](8); stage B0(kt+2) into cur buf =====
    // (B-half0 of cur is dead: all its reads completed by end of phase 1)
#pragma unroll
    for (int m = 0; m < 4; ++m) { LDA(a[m][0], 1, m, off, c0); LDA(a[m][1], 1, m, off, c1); }
    if (kt + 2 < NT) STAGE_B(kt + 2, 0);
    phase_split();
    asm volatile("s_waitcnt lgkmcnt(0)" ::: "memory");
    __builtin_amdgcn_sched_barrier(0);
    __builtin_amdgcn_s_setprio(1);
#pragma unroll
    for (int m = 0; m < 4; ++m)
#pragma unroll
      for (int n = 2; n < 4; ++n) {
        acc[4 + m][n] = __builtin_amdgcn_mfma_f32_16x16x32_bf16(a[m][0], bq[n][0], acc[4 + m][n], 0, 0, 0);
        acc[4 + m][n] = __builtin_amdgcn_mfma_f32_16x16x32_bf16(a[m][1], bq[n][1], acc[4 + m][n], 0, 0, 0);
      }
    __builtin_amdgcn_s_setprio(0);
    phase_split();

    // ============ phase 3: no reads; stage A0(kt+2); counted vmcnt ==========
    // (A-half0 of cur is dead: mh0 read at p0, mh1 at p2)
    if (kt + 2 < NT) STAGE_A(kt + 2, 0);
    phase_split();
    __builtin_amdgcn_s_setprio(1);
#pragma unroll
    for (int m = 0; m < 4; ++m)
#pragma unroll
      for (int n = 0; n < 2; ++n) {
        acc[4 + m][n] = __builtin_amdgcn_mfma_f32_16x16x32_bf16(a[m][0], bq[n][0], acc[4 + m][n], 0, 0, 0);
        acc[4 + m][n] = __builtin_amdgcn_mfma_f32_16x16x32_bf16(a[m][1], bq[n][1], acc[4 + m][n], 0, 0, 0);
      }
    __builtin_amdgcn_s_setprio(0);
    // wait for tile kt+1's 4 half-tiles; 4 loads (B0,A0 of kt+2) stay in flight
    if (kt + 2 < NT) {
      asm volatile("s_waitcnt vmcnt(4)" ::: "memory");
    } else if (kt + 1 < NT) {
      asm volatile("s_waitcnt vmcnt(0)" ::: "memory");
    }
    phase_split();
  }

#undef STAGE_A
#undef STAGE_B
#undef LDA
#undef LDB

  // ---- epilogue: D row=(lane>>4)*4+r (M), col=lane&15 (N); fused scale+bias
  const int rq   = (lane >> 4) << 2;
  const int colb = n0 + wc * 64 + (lane & 15);
#pragma unroll
  for (int ni = 0; ni < 4; ++ni) {
    const int col = colb + ni * 16;
    const float s_  = scales[col];
    const float bb  = bias[col];
#pragma unroll
    for (int mi = 0; mi < 8; ++mi) {
      const int rowb = m0 + wr * 128 + mi * 16 + rq;
#pragma unroll
      for (int r = 0; r < 4; ++r)
        out[(size_t)(rowb + r) * OUT_F + col] = acc[mi][ni][r] * s_ + bb;
    }
  }
}

extern "C" void kernel_launch(void* const* d_in, const int* in_sizes, int n_in,
                              void* d_out, int out_size, void* d_ws, size_t ws_size,
                              hipStream_t stream) {
  const float* x      = (const float*)d_in[0];
  const int*   wq     = (const int*)d_in[1];    // int8 values stored as int32 per harness contract
  const float* scales = (const float*)d_in[2];
  const float* bias   = (const float*)d_in[3];
  float* out = (float*)d_out;

  unsigned short* Xb = (unsigned short*)d_ws;                                      // 67 MB
  unsigned short* Wb = (unsigned short*)((char*)d_ws + (size_t)TOKENS * IN_F * 2); // +90 MB

  convert_x_kernel<<<TOKENS * IN_F / (256 * 8), 256, 0, stream>>>(x, Xb);
  convert_w_kernel<<<OUT_F * IN_F / (256 * 8), 256, 0, stream>>>(wq, Wb);
  qlinear_gemm<<<NWG, 512, 0, stream>>>(Xb, Wb, scales, bias, out);
}

// Round 5
// 1287.058 us; speedup vs baseline: 1.1204x; 1.0696x over previous
//
#include <hip/hip_runtime.h>

#define TOKENS 8192
#define IN_F   4096
#define OUT_F  11008

#define BM 256
#define BN 256
#define BK 64
#define NT (IN_F / BK)      // 64 K-tiles
#define TM (TOKENS / BM)    // 32
#define TN (OUT_F / BN)     // 43
#define NWG (TM * TN)       // 1376 = 8 XCDs * 172

#define LDS_TILE 32768      // 256 rows * 128 B
#define ROWB 128            // LDS row bytes (64 bf16)
#define GROWB (IN_F * 2)    // global row bytes = 8192

typedef __attribute__((ext_vector_type(8))) short bf16x8;
typedef __attribute__((ext_vector_type(4))) float floatx4;

__device__ __forceinline__ unsigned short f32_to_bf16(float f) {
  union { float f; unsigned int u; } v; v.f = f;
  unsigned int r = v.u + 0x7FFFu + ((v.u >> 16) & 1u);   // round-to-nearest-even
  return (unsigned short)(r >> 16);
}

__device__ __forceinline__ void gload_lds16(const void* g, void* l) {
  __builtin_amdgcn_global_load_lds(
      (const __attribute__((address_space(1))) void*)g,
      (__attribute__((address_space(3))) void*)l,
      16, 0, 0);
}

__device__ __forceinline__ void phase_split() {
  __builtin_amdgcn_sched_barrier(0);
  __builtin_amdgcn_s_barrier();
  __builtin_amdgcn_sched_barrier(0);
}

// ---- x: fp32 -> bf16 (8 elems/thread, 16B stores) ----
__global__ __launch_bounds__(256) void convert_x_kernel(
    const float* __restrict__ x, unsigned short* __restrict__ xb) {
  int idx = (blockIdx.x * 256 + threadIdx.x) * 8;
  const float4* p = (const float4*)(x + idx);
  float4 f0 = p[0], f1 = p[1];
  bf16x8 o;
  o[0] = (short)f32_to_bf16(f0.x); o[1] = (short)f32_to_bf16(f0.y);
  o[2] = (short)f32_to_bf16(f0.z); o[3] = (short)f32_to_bf16(f0.w);
  o[4] = (short)f32_to_bf16(f1.x); o[5] = (short)f32_to_bf16(f1.y);
  o[6] = (short)f32_to_bf16(f1.z); o[7] = (short)f32_to_bf16(f1.w);
  *(bf16x8*)(xb + idx) = o;
}

// ---- W: int32 (values in [-128,127]) -> bf16, exact ----
__global__ __launch_bounds__(256) void convert_w_kernel(
    const int* __restrict__ w, unsigned short* __restrict__ wb) {
  int idx = (blockIdx.x * 256 + threadIdx.x) * 8;
  const int4* p = (const int4*)(w + idx);
  int4 a = p[0], b = p[1];
  bf16x8 o;
  o[0] = (short)f32_to_bf16((float)a.x); o[1] = (short)f32_to_bf16((float)a.y);
  o[2] = (short)f32_to_bf16((float)a.z); o[3] = (short)f32_to_bf16((float)a.w);
  o[4] = (short)f32_to_bf16((float)b.x); o[5] = (short)f32_to_bf16((float)b.y);
  o[6] = (short)f32_to_bf16((float)b.z); o[7] = (short)f32_to_bf16((float)b.w);
  *(bf16x8*)(wb + idx) = o;
}

// ---- 256x256 8-phase bf16 GEMM (m201 template): C = A * B^T, fused scale+bias
// 512 threads = 8 waves (2M x 4N). BK=64, double-buffered 128 KiB LDS.
// Quadrant phases, one half-tile staged per phase, counted vmcnt(4)/K-tile.
// 16B-granule XOR swizzle; 2-D L2-aware XCD mapping (R1).
// R4 change (= R3 minus convert-kernel NT loads): nontemporal C stores only.
// C (360 MB/dispatch) is write-once and streams through L2/L3, evicting the
// A/B panels (FETCH 553 MB vs 150 MB unique, B re-fetched 4-6x from HBM).
__global__ __launch_bounds__(512, 2) void qlinear_gemm(
    const unsigned short* __restrict__ A,
    const unsigned short* __restrict__ B,
    const float* __restrict__ scales,
    const float* __restrict__ bias,
    float* __restrict__ out) {
  __shared__ __align__(16) char As[2 * LDS_TILE];
  __shared__ __align__(16) char Bs[2 * LDS_TILE];

  const int wg  = blockIdx.x;
  const int xcd = wg & 7;
  const int s   = wg >> 3;          // 0..171
  const int tm  = xcd * 4 + (s & 3);
  const int tn  = s >> 2;
  const int m0  = tm * BM;
  const int n0  = tn * BN;

  const int t    = threadIdx.x;
  const int lane = t & 63;
  const int w    = t >> 6;   // 0..7
  const int wr   = w >> 2;   // 0..1 (M)
  const int wc   = w & 3;    // 0..3 (N)

  // ---- staging geometry ----
  const int srow = (w << 3) + (lane >> 3);
  const int sgx  = ((lane & 7) ^ (lane >> 3)) << 4;
  const char* gA = (const char*)A + (size_t)(m0 + srow) * GROWB + sgx;
  const char* gB = (const char*)B + (size_t)(n0 + srow) * GROWB + sgx;
  char* lA = As + (w << 3) * ROWB;   // wave-uniform base; HW adds lane*16
  char* lB = Bs + (w << 3) * ROWB;

#define STAGE_A(tt, h) do {                                                  \
    const char* g_ = gA + (size_t)(tt) * (BK * 2) + (size_t)((h)*128) * GROWB; \
    char* l_ = lA + ((tt) & 1) * LDS_TILE + ((h) * 128) * ROWB;              \
    gload_lds16(g_, l_);                                                     \
    gload_lds16(g_ + (size_t)64 * GROWB, l_ + 64 * ROWB);                    \
  } while (0)

#define STAGE_B(tt, h) do {                                                  \
    const char* g_ = gB + (size_t)(tt) * (BK * 2) + (size_t)((h)*128) * GROWB; \
    char* l_ = lB + ((tt) & 1) * LDS_TILE + ((h) * 128) * ROWB;              \
    gload_lds16(g_, l_);                                                     \
    gload_lds16(g_ + (size_t)64 * GROWB, l_ + 64 * ROWB);                    \
  } while (0)

  // ---- read geometry: frag row = base + (lane&15); row&7 == lane&7 ----
  const int c0 = (((lane >> 4) ^ (lane & 7)) << 4);        // kk=0 granule byte
  const int c1 = ((((lane >> 4) | 4) ^ (lane & 7)) << 4);  // kk=1 granule byte
  const char* rA = As + (wr * 128 + (lane & 15)) * ROWB;
  const char* rB = Bs + (wc * 64 + (lane & 15)) * ROWB;

#define LDA(dst, mh, m, off, ck) \
  dst = *(const bf16x8*)(rA + (off) + ((mh) * 64 + (m) * 16) * ROWB + (ck))
#define LDB(dst, ni, off, ck) \
  dst = *(const bf16x8*)(rB + (off) + (ni) * 16 * ROWB + (ck))

  floatx4 acc[8][4];
#pragma unroll
  for (int i = 0; i < 8; ++i)
#pragma unroll
    for (int j = 0; j < 4; ++j) acc[i][j] = (floatx4){0.f, 0.f, 0.f, 0.f};

  // ---- prologue: tile0 {A0,A1,B0,B1} then tile1 {B0,A0}; wait tile0 (4 left)
  STAGE_A(0, 0); STAGE_A(0, 1); STAGE_B(0, 0); STAGE_B(0, 1);
  STAGE_B(1, 0); STAGE_A(1, 0);
  asm volatile("s_waitcnt vmcnt(4)" ::: "memory");
  phase_split();

  bf16x8 a[4][2];   // current A mh-half (reused mh0 -> mh1)
  bf16x8 bq[4][2];  // all 4 B n-frags, live across the 4 phases

  for (int kt = 0; kt < NT; ++kt) {
    const int off = (kt & 1) * LDS_TILE;

    // ============ phase 0: reads A[mh0](8) + B[n01](4); stage B1(kt+1) ======
#pragma unroll
    for (int m = 0; m < 4; ++m) { LDA(a[m][0], 0, m, off, c0); LDA(a[m][1], 0, m, off, c1); }
#pragma unroll
    for (int n = 0; n < 2; ++n) { LDB(bq[n][0], n, off, c0); LDB(bq[n][1], n, off, c1); }
    if (kt + 1 < NT) STAGE_B(kt + 1, 1);
    phase_split();
    asm volatile("s_waitcnt lgkmcnt(0)" ::: "memory");
    __builtin_amdgcn_sched_barrier(0);
    __builtin_amdgcn_s_setprio(1);
#pragma unroll
    for (int m = 0; m < 4; ++m)
#pragma unroll
      for (int n = 0; n < 2; ++n) {
        acc[m][n] = __builtin_amdgcn_mfma_f32_16x16x32_bf16(a[m][0], bq[n][0], acc[m][n], 0, 0, 0);
        acc[m][n] = __builtin_amdgcn_mfma_f32_16x16x32_bf16(a[m][1], bq[n][1], acc[m][n], 0, 0, 0);
      }
    __builtin_amdgcn_s_setprio(0);
    phase_split();

    // ============ phase 1: reads B[n23](4); stage A1(kt+1) ==================
#pragma unroll
    for (int n = 2; n < 4; ++n) { LDB(bq[n][0], n, off, c0); LDB(bq[n][1], n, off, c1); }
    if (kt + 1 < NT) STAGE_A(kt + 1, 1);
    phase_split();
    asm volatile("s_waitcnt lgkmcnt(0)" ::: "memory");
    __builtin_amdgcn_sched_barrier(0);
    __builtin_amdgcn_s_setprio(1);
#pragma unroll
    for (int m = 0; m < 4; ++m)
#pragma unroll
      for (int n = 2; n < 4; ++n) {
        acc[m][n] = __builtin_amdgcn_mfma_f32_16x16x32_bf16(a[m][0], bq[n][0], acc[m][n], 0, 0, 0);
        acc[m][n] = __builtin_amdgcn_mfma_f32_16x16x32_bf16(a[m][1], bq[n][1], acc[m][n], 0, 0, 0);
      }
    __builtin_amdgcn_s_setprio(0);
    phase_split();

    // ============ phase 2: reads A[mh1](8); stage B0(kt+2) ==================
#pragma unroll
    for (int m = 0; m < 4; ++m) { LDA(a[m][0], 1, m, off, c0); LDA(a[m][1], 1, m, off, c1); }
    if (kt + 2 < NT) STAGE_B(kt + 2, 0);
    phase_split();
    asm volatile("s_waitcnt lgkmcnt(0)" ::: "memory");
    __builtin_amdgcn_sched_barrier(0);
    __builtin_amdgcn_s_setprio(1);
#pragma unroll
    for (int m = 0; m < 4; ++m)
#pragma unroll
      for (int n = 2; n < 4; ++n) {
        acc[4 + m][n] = __builtin_amdgcn_mfma_f32_16x16x32_bf16(a[m][0], bq[n][0], acc[4 + m][n], 0, 0, 0);
        acc[4 + m][n] = __builtin_amdgcn_mfma_f32_16x16x32_bf16(a[m][1], bq[n][1], acc[4 + m][n], 0, 0, 0);
      }
    __builtin_amdgcn_s_setprio(0);
    phase_split();

    // ============ phase 3: no reads; stage A0(kt+2); counted vmcnt ==========
    if (kt + 2 < NT) STAGE_A(kt + 2, 0);
    phase_split();
    __builtin_amdgcn_s_setprio(1);
#pragma unroll
    for (int m = 0; m < 4; ++m)
#pragma unroll
      for (int n = 0; n < 2; ++n) {
        acc[4 + m][n] = __builtin_amdgcn_mfma_f32_16x16x32_bf16(a[m][0], bq[n][0], acc[4 + m][n], 0, 0, 0);
        acc[4 + m][n] = __builtin_amdgcn_mfma_f32_16x16x32_bf16(a[m][1], bq[n][1], acc[4 + m][n], 0, 0, 0);
      }
    __builtin_amdgcn_s_setprio(0);
    // wait for tile kt+1's 4 half-tiles; 4 loads (B0,A0 of kt+2) stay in flight
    if (kt + 2 < NT) {
      asm volatile("s_waitcnt vmcnt(4)" ::: "memory");
    } else if (kt + 1 < NT) {
      asm volatile("s_waitcnt vmcnt(0)" ::: "memory");
    }
    phase_split();
  }

#undef STAGE_A
#undef STAGE_B
#undef LDA
#undef LDB

  // ---- epilogue: D row=(lane>>4)*4+r (M), col=lane&15 (N); fused scale+bias
  // Nontemporal: C is write-once; keep it out of L2/L3 so A/B panels survive.
  const int rq   = (lane >> 4) << 2;
  const int colb = n0 + wc * 64 + (lane & 15);
#pragma unroll
  for (int ni = 0; ni < 4; ++ni) {
    const int col = colb + ni * 16;
    const float s_  = scales[col];
    const float bb  = bias[col];
#pragma unroll
    for (int mi = 0; mi < 8; ++mi) {
      const int rowb = m0 + wr * 128 + mi * 16 + rq;
#pragma unroll
      for (int r = 0; r < 4; ++r)
        __builtin_nontemporal_store(acc[mi][ni][r] * s_ + bb,
                                    &out[(size_t)(rowb + r) * OUT_F + col]);
    }
  }
}

extern "C" void kernel_launch(void* const* d_in, const int* in_sizes, int n_in,
                              void* d_out, int out_size, void* d_ws, size_t ws_size,
                              hipStream_t stream) {
  const float* x      = (const float*)d_in[0];
  const int*   wq     = (const int*)d_in[1];    // int8 values stored as int32 per harness contract
  const float* scales = (const float*)d_in[2];
  const float* bias   = (const float*)d_in[3];
  float* out = (float*)d_out;

  unsigned short* Xb = (unsigned short*)d_ws;                                      // 67 MB
  unsigned short* Wb = (unsigned short*)((char*)d_ws + (size_t)TOKENS * IN_F * 2); // +90 MB

  convert_x_kernel<<<TOKENS * IN_F / (256 * 8), 256, 0, stream>>>(x, Xb);
  convert_w_kernel<<<OUT_F * IN_F / (256 * 8), 256, 0, stream>>>(wq, Wb);
  qlinear_gemm<<<NWG, 512, 0, stream>>>(Xb, Wb, scales, bias, out);
}